// Round 2
// baseline (499.718 us; speedup 1.0000x reference)
//
#include <hip/hip_runtime.h>

#define NTAPS   63
#define PAD     31
#define NBATCH  32
#define SAMPLES 2097152
#define ROUT    16              // outputs per thread
#define BLOCK   256
#define CHUNK   (ROUT * BLOCK)  // 4096 outputs per block
#define WN      80              // window floats per thread (ROUT + 62, aligned up)

// Kernel 1: filt[b][t] = bias[t] + sum_k b[b][k] * W[t][k]   (b @ W.T + bias)
__global__ void filt_kernel(const float* __restrict__ b,
                            const float* __restrict__ W,
                            const float* __restrict__ bias,
                            float* __restrict__ filt) {
    const int batch = blockIdx.x;
    const int t = threadIdx.x;
    if (t < NTAPS) {
        const float* br = b + batch * NTAPS;
        const float* wr = W + t * NTAPS;
        float s = bias[t];
#pragma unroll
        for (int k = 0; k < NTAPS; ++k) s = fmaf(br[k], wr[k], s);
        filt[batch * NTAPS + t] = s;
    }
}

// Kernel 2: register sliding-window FIR.
// y[b][s] = sum_t filt[b][t] * x[b][s + t - PAD]  (zero outside [0,SAMPLES))
__global__ __launch_bounds__(BLOCK) void fir_kernel(const float* __restrict__ x,
                                                    const float* __restrict__ filt,
                                                    float* __restrict__ y) {
    const int batch = blockIdx.y;
    const int s0 = blockIdx.x * CHUNK + threadIdx.x * ROUT;  // first output sample
    const float* __restrict__ xb = x + (size_t)batch * SAMPLES;
    float*       __restrict__ yb = y + (size_t)batch * SAMPLES;
    const float* __restrict__ bf = filt + batch * NTAPS;     // uniform -> s_load

    // window covers [s0 - 32, s0 + 48): w[i] = x[s0 - 32 + i]
    // needed: x[s0 + r + t - 31] for r in [0,16), t in [0,63) -> w[r+t+1], idx 1..78
    float w[WN];
    const int base = s0 - 32;

    if (blockIdx.x != 0 && blockIdx.x != gridDim.x - 1) {
        // interior: whole window in range, aligned float4 loads
#pragma unroll
        for (int j = 0; j < WN / 4; ++j) {
            const float4 v = *reinterpret_cast<const float4*>(xb + base + 4 * j);
            w[4 * j + 0] = v.x;
            w[4 * j + 1] = v.y;
            w[4 * j + 2] = v.z;
            w[4 * j + 3] = v.w;
        }
    } else {
        // edge blocks: guarded loads, zero-pad outside [0, SAMPLES)
#pragma unroll
        for (int j = 0; j < WN / 4; ++j) {
            const int i = base + 4 * j;
            if (i >= 0 && i + 4 <= SAMPLES) {
                const float4 v = *reinterpret_cast<const float4*>(xb + i);
                w[4 * j + 0] = v.x;
                w[4 * j + 1] = v.y;
                w[4 * j + 2] = v.z;
                w[4 * j + 3] = v.w;
            } else {
#pragma unroll
                for (int e = 0; e < 4; ++e) {
                    const int ii = i + e;
                    w[4 * j + e] = (ii >= 0 && ii < SAMPLES) ? xb[ii] : 0.0f;
                }
            }
        }
    }

    float acc[ROUT];
#pragma unroll
    for (int r = 0; r < ROUT; ++r) acc[r] = 0.0f;

#pragma unroll
    for (int t = 0; t < NTAPS; ++t) {
        const float c = bf[t];  // SGPR
#pragma unroll
        for (int r = 0; r < ROUT; ++r) acc[r] = fmaf(c, w[r + t + 1], acc[r]);
    }

#pragma unroll
    for (int j = 0; j < ROUT / 4; ++j) {
        float4 v;
        v.x = acc[4 * j + 0];
        v.y = acc[4 * j + 1];
        v.z = acc[4 * j + 2];
        v.w = acc[4 * j + 3];
        *reinterpret_cast<float4*>(yb + s0 + 4 * j) = v;
    }
}

extern "C" void kernel_launch(void* const* d_in, const int* in_sizes, int n_in,
                              void* d_out, int out_size, void* d_ws, size_t ws_size,
                              hipStream_t stream) {
    const float* x    = (const float*)d_in[0];  // (32, 1, 2097152)
    const float* b    = (const float*)d_in[1];  // (32, 63)
    const float* W    = (const float*)d_in[2];  // (63, 63)
    const float* bias = (const float*)d_in[3];  // (63,)
    float* y = (float*)d_out;                   // (32, 1, 2097152)
    float* filt = (float*)d_ws;                 // 32*63 floats = 8064 B scratch

    filt_kernel<<<dim3(NBATCH), dim3(64), 0, stream>>>(b, W, bias, filt);

    dim3 grid(SAMPLES / CHUNK, NBATCH);  // (512, 32)
    fir_kernel<<<grid, dim3(BLOCK), 0, stream>>>(x, filt, y);
}

// Round 6
// 448.786 us; speedup vs baseline: 1.1135x; 1.1135x over previous
//
#include <hip/hip_runtime.h>

#define NTAPS   63
#define NBATCH  32
#define SAMPLES 2097152
#define ROUT    16                    // outputs per thread
#define BLOCK   256
#define CHUNK   (ROUT * BLOCK)        // 4096 outputs per block
#define TILE_F  (CHUNK + 64)          // 4160 floats incl. 32-left / 32-right halo
#define TILE_B  (TILE_F / 4)          // 1040 float4 blocks
// padded slot: insert one pad float4 per 4 -> balances LDS banks for both the
// coalesced writes and the 80B-lane-stride window reads (all 32 banks hit evenly)
#define PSLOT(o) ((o) + ((o) >> 2))
#define LDS_B   (PSLOT(TILE_B - 1) + 1)   // 1299 float4 = 20784 B

// Kernel 1: filt[b][t] = bias[t] + sum_k b[b][k] * W[t][k]   (b @ W.T + bias)
__global__ void filt_kernel(const float* __restrict__ b,
                            const float* __restrict__ W,
                            const float* __restrict__ bias,
                            float* __restrict__ filt) {
    const int batch = blockIdx.x;
    const int t = threadIdx.x;
    if (t < NTAPS) {
        const float* br = b + batch * NTAPS;
        const float* wr = W + t * NTAPS;
        float s = bias[t];
#pragma unroll
        for (int k = 0; k < NTAPS; ++k) s = fmaf(br[k], wr[k], s);
        filt[batch * NTAPS + t] = s;
    }
}

// Kernel 2: LDS-staged register sliding-window FIR.
__global__ __launch_bounds__(BLOCK) void fir_kernel(const float* __restrict__ x,
                                                    const float* __restrict__ filt,
                                                    float* __restrict__ y) {
    __shared__ float4 tile[LDS_B];

    const int tid = threadIdx.x;
    const int batch = blockIdx.y;
    const int chunk0 = blockIdx.x * CHUNK;            // first output of block
    const float* __restrict__ xb = x + (size_t)batch * SAMPLES;
    float*       __restrict__ yb = y + (size_t)batch * SAMPLES;
    const float* __restrict__ bf = filt + batch * NTAPS;   // uniform -> s_load

    // ---- stage tile: lds float g = x[chunk0 - 32 + g], zero outside ----
    const bool interior = (blockIdx.x != 0) && (blockIdx.x != gridDim.x - 1);
    if (interior) {
#pragma unroll
        for (int r = 0; r < 4; ++r) {
            const int o = r * BLOCK + tid;            // float4 block in tile
            const float4 v = *reinterpret_cast<const float4*>(xb + chunk0 - 32 + 4 * o);
            tile[PSLOT(o)] = v;
        }
        if (tid < TILE_B - 4 * BLOCK) {               // tail: 16 blocks
            const int o = 4 * BLOCK + tid;
            const float4 v = *reinterpret_cast<const float4*>(xb + chunk0 - 32 + 4 * o);
            tile[PSLOT(o)] = v;
        }
    } else {
#pragma unroll
        for (int r = 0; r < 5; ++r) {
            const int o = r * BLOCK + tid;
            if (o < TILE_B) {
                const int gi = chunk0 - 32 + 4 * o;
                float4 v;
                v.x = (gi + 0 >= 0 && gi + 0 < SAMPLES) ? xb[gi + 0] : 0.0f;
                v.y = (gi + 1 >= 0 && gi + 1 < SAMPLES) ? xb[gi + 1] : 0.0f;
                v.z = (gi + 2 >= 0 && gi + 2 < SAMPLES) ? xb[gi + 2] : 0.0f;
                v.w = (gi + 3 >= 0 && gi + 3 < SAMPLES) ? xb[gi + 3] : 0.0f;
                tile[PSLOT(o)] = v;
            }
        }
    }
    __syncthreads();

    // ---- window from LDS: w[i] = tile float (tid*16 + i) = x[s0 - 32 + i] ----
    float w[80];
#pragma unroll
    for (int j = 0; j < 20; ++j) {
        // PSLOT(4*tid + j) = 5*tid + j + (j>>2); lane stride = 5 blocks = 80 B
        const float4 v = tile[5 * tid + j + (j >> 2)];
        w[4 * j + 0] = v.x;
        w[4 * j + 1] = v.y;
        w[4 * j + 2] = v.z;
        w[4 * j + 3] = v.w;
    }

    float acc[ROUT];
#pragma unroll
    for (int r = 0; r < ROUT; ++r) acc[r] = 0.0f;

#pragma unroll
    for (int t = 0; t < NTAPS; ++t) {
        const float c = bf[t];                        // SGPR (uniform address)
#pragma unroll
        for (int r = 0; r < ROUT; ++r) acc[r] = fmaf(c, w[r + t + 1], acc[r]);
    }

    const int s0 = chunk0 + tid * ROUT;
#pragma unroll
    for (int j = 0; j < ROUT / 4; ++j) {
        float4 v;
        v.x = acc[4 * j + 0];
        v.y = acc[4 * j + 1];
        v.z = acc[4 * j + 2];
        v.w = acc[4 * j + 3];
        *reinterpret_cast<float4*>(yb + s0 + 4 * j) = v;
    }
}

extern "C" void kernel_launch(void* const* d_in, const int* in_sizes, int n_in,
                              void* d_out, int out_size, void* d_ws, size_t ws_size,
                              hipStream_t stream) {
    const float* x    = (const float*)d_in[0];  // (32, 1, 2097152)
    const float* b    = (const float*)d_in[1];  // (32, 63)
    const float* W    = (const float*)d_in[2];  // (63, 63)
    const float* bias = (const float*)d_in[3];  // (63,)
    float* y = (float*)d_out;                   // (32, 1, 2097152)
    float* filt = (float*)d_ws;                 // 32*63 floats scratch

    filt_kernel<<<dim3(NBATCH), dim3(64), 0, stream>>>(b, W, bias, filt);

    dim3 grid(SAMPLES / CHUNK, NBATCH);  // (512, 32)
    fir_kernel<<<grid, dim3(BLOCK), 0, stream>>>(x, filt, y);
}